// Round 6
// baseline (726.314 us; speedup 1.0000x reference)
//
#include <hip/hip_runtime.h>

// Problem constants
#define BATCH 4
#define SEQ 4096
#define DM 1024
#define HALF_D 512             // DM/2 rope pairs
#define NROWS (BATCH * SEQ)    // 16384
#define NT128 528              // 32*33/2 lower-tri 128x128 tiles per batch
#define TILE_ELE 16384         // 128*128
#define NTRI256 136            // 16*17/2 lower-tri 256-tiles per batch
#define NTILES_S 544           // 4 * 136

typedef _Float16 f16x8 __attribute__((ext_vector_type(8)));
typedef _Float16 f16x4 __attribute__((ext_vector_type(4)));
typedef _Float16 f16x2 __attribute__((ext_vector_type(2)));
typedef float f32x4 __attribute__((ext_vector_type(4)));

#define AS1(p) ((const __attribute__((address_space(1))) void*)(p))
#define AS3(p) ((__attribute__((address_space(3))) void*)(p))

// ---------------- fused fp32 -> fp16 convert (x + wq + wk + wv) ----------------
__global__ __launch_bounds__(256) void cvt_all(
    const float* __restrict__ x, const float* __restrict__ wq,
    const float* __restrict__ wk, const float* __restrict__ wv,
    _Float16* __restrict__ xh, _Float16* __restrict__ wh /* wqh base */) {
  int i = blockIdx.x * 256 + threadIdx.x;
  const int NX = NROWS * DM / 8;  // 2097152
  const int NW = DM * DM / 8;     // 131072
  const float* src;
  _Float16* dst;
  int so;
  if (i < NX) {
    src = x; so = i; dst = xh + 8 * (size_t)i;
  } else {
    int j = i - NX;
    if (j >= 3 * NW) return;
    dst = wh + 8 * (size_t)j;  // wqh/wkh/wvh contiguous in ws
    if (j < NW) { src = wq; so = j; }
    else if (j < 2 * NW) { src = wk; so = j - NW; }
    else { src = wv; so = j - 2 * NW; }
  }
  const float4* s4 = (const float4*)src;
  float4 a = s4[2 * so], b = s4[2 * so + 1];
  f16x8 h;
  h[0] = (_Float16)a.x; h[1] = (_Float16)a.y;
  h[2] = (_Float16)a.z; h[3] = (_Float16)a.w;
  h[4] = (_Float16)b.x; h[5] = (_Float16)b.y;
  h[6] = (_Float16)b.z; h[7] = (_Float16)b.w;
  *(f16x8*)dst = h;
}

// ---------------- RoPE apply in place; single launch covers q AND k ----------------
// (qh and kh are contiguous; rows 16384..32767 are kh, pos = row & 4095 still valid)
__global__ __launch_bounds__(256) void rope_apply(_Float16* __restrict__ T) {
  int idx = blockIdx.x * 256 + threadIdx.x;  // 2*NROWS*HALF_D
  int row = idx >> 9;
  int i = idx & 511;
  int pos = row & (SEQ - 1);
  float theta = expf(-0.017988946039016f * ((float)i - 1.0f));  // 10000^(-2(i-1)/DM)
  float ang = (float)pos * theta;
  float c = cosf(ang), s = sinf(ang);
  f16x2 p = ((f16x2*)T)[idx];
  float e = (float)p[0], o = (float)p[1];
  p[0] = (_Float16)(e * c + o * s);
  p[1] = (_Float16)(o * c - e * s);
  ((f16x2*)T)[idx] = p;
}

// =====================================================================
// PERSISTENT 256x256-tile 8-phase NT GEMM (m201-style, f16).
// Per-slot phase/barrier/vmcnt structure identical to round-4 (verified):
//   phase1: issue B(s+1) -> dbuf[(s+1)&1]; ds_read af0-3,bf0-1; bar; G0; bar
//   phase2: ds_read bf2-3; bar; G1; bar
//   phase3: ds_read af4-7; bar; G2; bar
//   phase4: issue A(s+2) -> dbuf[s&1]; G3; vmcnt(4); bar
// Persistence: slots run over a per-block TILE LIST; staging targets cross
// tile boundaries via cur/next descriptors (LDS parity continuous, NKT even).
// Epilogue at kt==15 overlaps the already-in-flight next-tile loads; its
// stores retire to L2 under the next tile's phases.
// MODE 4 (qkv): 256 blocks, block=(by,bx), tiles = {Q,K,V} same panels.
// MODE 1 (scores): 256 blocks, tiles {bid, bid+256, bid+512} < 544 tri-tiles.
// =====================================================================
template <int MODE>
__global__ __launch_bounds__(512, 2) void gemm_p(
    const _Float16* __restrict__ Abase, const _Float16* __restrict__ W0,
    const _Float16* __restrict__ W1, const _Float16* __restrict__ W2,
    _Float16* __restrict__ O0, _Float16* __restrict__ O1,
    _Float16* __restrict__ O2) {
  extern __shared__ __align__(16) _Float16 lds[];  // 128 KiB
  const int bid = blockIdx.x;
  const int tid = threadIdx.x;
  const int lane = tid & 63, wave = tid >> 6;
  const int wr = wave >> 2, wc = wave & 3;  // 2x4 wave grid
  const int r16 = lane & 15, quad = lane >> 4;

  // per-thread staging offsets (lda = ldb = DM), source col pre-swizzled
  int offs[2][2];
#pragma unroll
  for (int i = 0; i < 2; ++i) {
    int c = i * 512 + tid;
    int row = c >> 3;
    int scol = (c & 7) ^ (row & 7);
#pragma unroll
    for (int h = 0; h < 2; ++h) offs[h][i] = (h * 128 + row) * DM + scol * 8;
  }

  // ---- tile descriptors (cur / next) ----
  int nt;
  const _Float16 *cA, *cB, *nA, *nB;
  int c_by = 0, c_bx = 0, c_bz = 0, n_by = 0, n_bx = 0, n_bz = 0;
  const int qm0 = (bid >> 2) * 256, qn0 = (bid & 3) * 256;  // MODE 4 geometry

  if (MODE == 4) {
    nt = 3;
    cA = Abase + (size_t)qm0 * DM;
    nA = cA;  // X panel shared by all three projections
    cB = W0 + (size_t)qn0 * DM;
    nB = W1 + (size_t)qn0 * DM;
  } else {
    nt = (bid + 512 < NTILES_S) ? 3 : 2;
    // decode tri-tile ids bid and bid+256
    int id0 = bid, id1 = bid + 256;
    {
      int bz = id0 / NTRI256, r = id0 - bz * NTRI256;
      int b = (int)((sqrtf(8.f * r + 1.f) - 1.f) * 0.5f);
      while ((b + 1) * (b + 2) / 2 <= r) ++b;
      while (b * (b + 1) / 2 > r) --b;
      c_bz = bz; c_by = b; c_bx = r - b * (b + 1) / 2;
      cA = Abase + ((size_t)bz * SEQ + (size_t)c_by * 256) * DM;
      cB = W0 + ((size_t)bz * SEQ + (size_t)c_bx * 256) * DM;
    }
    {
      int bz = id1 / NTRI256, r = id1 - bz * NTRI256;
      int b = (int)((sqrtf(8.f * r + 1.f) - 1.f) * 0.5f);
      while ((b + 1) * (b + 2) / 2 <= r) ++b;
      while (b * (b + 1) / 2 > r) --b;
      n_bz = bz; n_by = b; n_bx = r - b * (b + 1) / 2;
      nA = Abase + ((size_t)bz * SEQ + (size_t)n_by * 256) * DM;
      nB = W0 + ((size_t)bz * SEQ + (size_t)n_bx * 256) * DM;
    }
  }

#define STAGE_A(BASE, ktv, dd)                                              \
  {                                                                         \
    _Pragma("unroll") for (int i = 0; i < 2; ++i) {                         \
      int cu = (i * 512 + wave * 64) * 8;                                   \
      _Pragma("unroll") for (int h = 0; h < 2; ++h)                         \
          __builtin_amdgcn_global_load_lds(                                 \
              AS1(BASE + offs[h][i] + (ktv) * 64),                          \
              AS3(&lds[((dd) * 4 + h) * 8192 + cu]), 16, 0, 0);             \
    }                                                                       \
  }
#define STAGE_B(BASE, ktv, dd)                                              \
  {                                                                         \
    _Pragma("unroll") for (int i = 0; i < 2; ++i) {                         \
      int cu = (i * 512 + wave * 64) * 8;                                   \
      _Pragma("unroll") for (int h = 0; h < 2; ++h)                         \
          __builtin_amdgcn_global_load_lds(                                 \
              AS1(BASE + offs[h][i] + (ktv) * 64),                          \
              AS3(&lds[((dd) * 4 + 2 + h) * 8192 + cu]), 16, 0, 0);         \
    }                                                                       \
  }

  f32x4 acc[8][4] = {};
  const int aoff0 = ((quad) ^ (r16 & 7)) * 8;
  const int aoff1 = ((4 + quad) ^ (r16 & 7)) * 8;
  const int NS = nt * 16;

  // prologue: A0,B0 of tile 0 + A1 in flight; wait tile0 kt0
  STAGE_A(cA, 0, 0);
  STAGE_B(cB, 0, 0);
  STAGE_A(cA, 1, 1);
  asm volatile("s_waitcnt vmcnt(4)" ::: "memory");
  __builtin_amdgcn_s_barrier();

  int s = 0;
  for (int j = 0; j < nt; ++j) {
    for (int kt = 0; kt < 16; ++kt, ++s) {
      const int d = s & 1;
      const _Float16* Ab = lds + (d * 4 + wr) * 8192;
      const _Float16* Bb =
          lds + (d * 4 + 2 + (wc >> 1)) * 8192 + (wc & 1) * 4096;
      f16x8 af[4][2], bf[4][2];

      // phase 1: issue B(s+1); read af(0-3)+bf(0-1); MFMA G0
      if (s + 1 < NS) {
        if (kt < 15) { STAGE_B(cB, kt + 1, d ^ 1); }
        else         { STAGE_B(nB, 0, d ^ 1); }
      }
#pragma unroll
      for (int mi = 0; mi < 4; ++mi) {
        af[mi][0] = *(const f16x8*)&Ab[(mi * 16 + r16) * 64 + aoff0];
        af[mi][1] = *(const f16x8*)&Ab[(mi * 16 + r16) * 64 + aoff1];
      }
#pragma unroll
      for (int ni = 0; ni < 2; ++ni) {
        bf[ni][0] = *(const f16x8*)&Bb[(ni * 16 + r16) * 64 + aoff0];
        bf[ni][1] = *(const f16x8*)&Bb[(ni * 16 + r16) * 64 + aoff1];
      }
      __builtin_amdgcn_s_barrier();
      __builtin_amdgcn_s_setprio(1);
#pragma unroll
      for (int mi = 0; mi < 4; ++mi)
#pragma unroll
        for (int ni = 0; ni < 2; ++ni) {
          acc[mi][ni] = __builtin_amdgcn_mfma_f32_16x16x32_f16(
              af[mi][0], bf[ni][0], acc[mi][ni], 0, 0, 0);
          acc[mi][ni] = __builtin_amdgcn_mfma_f32_16x16x32_f16(
              af[mi][1], bf[ni][1], acc[mi][ni], 0, 0, 0);
        }
      __builtin_amdgcn_s_setprio(0);
      __builtin_amdgcn_s_barrier();

      // phase 2: read bf(2-3); MFMA G1
#pragma unroll
      for (int ni = 2; ni < 4; ++ni) {
        bf[ni][0] = *(const f16x8*)&Bb[(ni * 16 + r16) * 64 + aoff0];
        bf[ni][1] = *(const f16x8*)&Bb[(ni * 16 + r16) * 64 + aoff1];
      }
      __builtin_amdgcn_s_barrier();
      __builtin_amdgcn_s_setprio(1);
#pragma unroll
      for (int mi = 0; mi < 4; ++mi)
#pragma unroll
        for (int ni = 2; ni < 4; ++ni) {
          acc[mi][ni] = __builtin_amdgcn_mfma_f32_16x16x32_f16(
              af[mi][0], bf[ni][0], acc[mi][ni], 0, 0, 0);
          acc[mi][ni] = __builtin_amdgcn_mfma_f32_16x16x32_f16(
              af[mi][1], bf[ni][1], acc[mi][ni], 0, 0, 0);
        }
      __builtin_amdgcn_s_setprio(0);
      __builtin_amdgcn_s_barrier();

      // phase 3: read af(4-7); MFMA G2
#pragma unroll
      for (int mi = 0; mi < 4; ++mi) {
        af[mi][0] = *(const f16x8*)&Ab[((mi + 4) * 16 + r16) * 64 + aoff0];
        af[mi][1] = *(const f16x8*)&Ab[((mi + 4) * 16 + r16) * 64 + aoff1];
      }
      __builtin_amdgcn_s_barrier();
      __builtin_amdgcn_s_setprio(1);
#pragma unroll
      for (int mi = 0; mi < 4; ++mi)
#pragma unroll
        for (int ni = 0; ni < 2; ++ni) {
          acc[mi + 4][ni] = __builtin_amdgcn_mfma_f32_16x16x32_f16(
              af[mi][0], bf[ni][0], acc[mi + 4][ni], 0, 0, 0);
          acc[mi + 4][ni] = __builtin_amdgcn_mfma_f32_16x16x32_f16(
              af[mi][1], bf[ni][1], acc[mi + 4][ni], 0, 0, 0);
        }
      __builtin_amdgcn_s_setprio(0);
      __builtin_amdgcn_s_barrier();
      // all waves' reads of dbuf[d] are complete

      // phase 4: issue A(s+2) -> dbuf[d]; MFMA G3; counted wait
      if (s + 2 < NS) {
        if (kt < 14) { STAGE_A(cA, kt + 2, d); }
        else         { STAGE_A(nA, kt - 14, d); }
      }
      __builtin_amdgcn_s_setprio(1);
#pragma unroll
      for (int mi = 0; mi < 4; ++mi)
#pragma unroll
        for (int ni = 2; ni < 4; ++ni) {
          acc[mi + 4][ni] = __builtin_amdgcn_mfma_f32_16x16x32_f16(
              af[mi][0], bf[ni][0], acc[mi + 4][ni], 0, 0, 0);
          acc[mi + 4][ni] = __builtin_amdgcn_mfma_f32_16x16x32_f16(
              af[mi][1], bf[ni][1], acc[mi + 4][ni], 0, 0, 0);
        }
      __builtin_amdgcn_s_setprio(0);
      if (s + 2 < NS) {
        asm volatile("s_waitcnt vmcnt(4)" ::: "memory");  // slot s+1 landed
      } else if (s + 1 < NS) {
        asm volatile("s_waitcnt vmcnt(0)" ::: "memory");
      }
      __builtin_amdgcn_s_barrier();
    }

    // ---- epilogue for tile j (overlaps next tile's in-flight loads) ----
    if (MODE == 4) {
      if (j < 2) {  // Q or K: row-major fp16
        _Float16* C = (_Float16*)(j == 0 ? O0 : O1);
#pragma unroll
        for (int mi = 0; mi < 8; ++mi)
#pragma unroll
          for (int ni = 0; ni < 4; ++ni)
#pragma unroll
            for (int r = 0; r < 4; ++r) {
              int grow = qm0 + wr * 128 + mi * 16 + quad * 4 + r;
              int gcol = qn0 + wc * 64 + ni * 16 + r16;
              C[(size_t)grow * DM + gcol] = (_Float16)acc[mi][ni][r];
            }
      } else {  // V -> Vt[b][d][m]
#pragma unroll
        for (int mi = 0; mi < 8; ++mi)
#pragma unroll
          for (int ni = 0; ni < 4; ++ni) {
            int gcol = qn0 + wc * 64 + ni * 16 + r16;         // d
            int growb = qm0 + wr * 128 + mi * 16 + quad * 4;  // m base
            int b = growb >> 12;
            int m = growb & (SEQ - 1);
            f16x4 t;
#pragma unroll
            for (int r = 0; r < 4; ++r) t[r] = (_Float16)acc[mi][ni][r];
            *(f16x4*)&O2[((size_t)b * DM + gcol) * SEQ + m] = t;
          }
      }
    } else {  // MODE 1: 128x128 quadrants into packed lower-tri layout
      int i128 = c_by * 2 + wr;
      int j128 = c_bx * 2 + (wc >> 1);
      if (j128 <= i128) {
        _Float16* T = O0 + (size_t)c_bz * ((size_t)NT128 * TILE_ELE) +
                      (size_t)(i128 * (i128 + 1) / 2 + j128) * TILE_ELE;
#pragma unroll
        for (int mi = 0; mi < 8; ++mi)
#pragma unroll
          for (int ni = 0; ni < 4; ++ni)
#pragma unroll
            for (int r = 0; r < 4; ++r) {
              int lr = mi * 16 + quad * 4 + r;         // 0..127
              int lc = (wc & 1) * 64 + ni * 16 + r16;  // 0..127
              T[lr * 128 + lc] = (_Float16)(acc[mi][ni][r] * 0.03125f);
            }
      }
    }

    // reset accumulators
#pragma unroll
    for (int mi = 0; mi < 8; ++mi)
#pragma unroll
      for (int ni = 0; ni < 4; ++ni)
#pragma unroll
        for (int r = 0; r < 4; ++r) acc[mi][ni][r] = 0.f;

    // shift descriptors cur <- next; compute new next (tile j+2) if it exists
    if (j + 1 < nt) {
      cA = nA; cB = nB;
      c_by = n_by; c_bx = n_bx; c_bz = n_bz;
      if (MODE == 4) {
        nB = W2 + (size_t)qn0 * DM;  // only meaningful after j==0
      } else {
        int id2 = bid + 256 * (j + 2);
        if (id2 < NTILES_S) {
          int bz = id2 / NTRI256, r = id2 - bz * NTRI256;
          int b = (int)((sqrtf(8.f * r + 1.f) - 1.f) * 0.5f);
          while ((b + 1) * (b + 2) / 2 <= r) ++b;
          while (b * (b + 1) / 2 > r) --b;
          n_bz = bz; n_by = b; n_bx = r - b * (b + 1) / 2;
          nA = Abase + ((size_t)bz * SEQ + (size_t)n_by * 256) * DM;
          nB = W0 + ((size_t)bz * SEQ + (size_t)n_bx * 256) * DM;
        }
      }
    }
  }
#undef STAGE_A
#undef STAGE_B
}

// =====================================================================
// PV: O = P @ V, 128x256-tile NT GEMM, BK=64, 8 waves (2x4), 64x64/wave.
// (unchanged from round 4 — verified)
// =====================================================================
__global__ __launch_bounds__(512, 1) void gemm_pv(
    const _Float16* __restrict__ P, const _Float16* __restrict__ Vt,
    float* __restrict__ O) {
  const int id = blockIdx.x;
  const int by = 31 - (id >> 4);  // heavy (large K) first
  const int bx = id & 3;          // DM/256 col-tile
  const int bz = (id >> 2) & 3;   // batch

  extern __shared__ __align__(16) _Float16 lds[];  // 49152 f16 = 96 KiB

  const int tid = threadIdx.x;
  const int lane = tid & 63, wave = tid >> 6;
  const int wr = wave >> 2, wc = wave & 3;
  const int r16 = lane & 15, quad = lane >> 4;
  const int n0 = bx * 256;

  const _Float16* Pb = P + (size_t)bz * ((size_t)NT128 * TILE_ELE) +
                       (size_t)(by * (by + 1) / 2) * TILE_ELE;
  const _Float16* Vb = Vt + (size_t)bz * ((size_t)DM * SEQ) + (size_t)n0 * SEQ;

  const int NKT = (by + 1) * 2;  // even, >= 2

#define PV_STAGE(t, dd)                                                      \
  {                                                                          \
    _Pragma("unroll") for (int i = 0; i < 2; ++i) {                          \
      int c = i * 512 + tid;                                                 \
      int row = c >> 3;                                                      \
      int scol = (c & 7) ^ (row & 7);                                        \
      const _Float16* gA = Pb + (size_t)((t) >> 1) * TILE_ELE + row * 128 +  \
                           ((t) & 1) * 64 + scol * 8;                        \
      __builtin_amdgcn_global_load_lds(                                      \
          AS1(gA), AS3(&lds[(dd) * 24576 + (i * 512 + wave * 64) * 8]), 16,  \
          0, 0);                                                             \
    }                                                                        \
    _Pragma("unroll") for (int i = 0; i < 4; ++i) {                          \
      int c = i * 512 + tid;                                                 \
      int row = c >> 3;                                                      \
      int scol = (c & 7) ^ (row & 7);                                        \
      const _Float16* gB = Vb + (size_t)row * SEQ + (t) * 64 + scol * 8;     \
      __builtin_amdgcn_global_load_lds(                                      \
          AS1(gB),                                                           \
          AS3(&lds[(dd) * 24576 + 8192 + (i * 512 + wave * 64) * 8]), 16, 0, \
          0);                                                                \
    }                                                                        \
  }

  f32x4 acc[4][4] = {};

  const int aoff0 = ((quad) ^ (r16 & 7)) * 8;
  const int aoff1 = ((4 + quad) ^ (r16 & 7)) * 8;
  const int arow = (wr * 64 + r16) * 64;
  const int brow = (wc * 64 + r16) * 64;

  PV_STAGE(0, 0);
  PV_STAGE(1, 1);
  asm volatile("s_waitcnt vmcnt(6)" ::: "memory");
  __builtin_amdgcn_s_barrier();

  for (int kt = 0; kt < NKT; ++kt) {
    const int d = kt & 1;
    const _Float16* Ab = lds + d * 24576;
    const _Float16* Bb = Ab + 8192;
    f16x8 af[4][2], bf[4][2];

#pragma unroll
    for (int mi = 0; mi < 4; ++mi) {
      af[mi][0] = *(const f16x8*)&Ab[arow + mi * 16 * 64 + aoff0];
      af[mi][1] = *(const f16x8*)&Ab[arow + mi * 16 * 64 + aoff1];
    }
#pragma unroll
    for (int ni = 0; ni < 4; ++ni) {
      bf[ni][0] = *(const f16x8*)&Bb[brow + ni * 16 * 64 + aoff0];
      bf[ni][1] = *(const f16x8*)&Bb[brow + ni * 16 * 64 + aoff1];
    }
    __builtin_amdgcn_s_barrier();
    __builtin_amdgcn_s_setprio(1);
#pragma unroll
    for (int mi = 0; mi < 4; ++mi)
#pragma unroll
      for (int ni = 0; ni < 2; ++ni) {
        acc[mi][ni] = __builtin_amdgcn_mfma_f32_16x16x32_f16(
            af[mi][0], bf[ni][0], acc[mi][ni], 0, 0, 0);
        acc[mi][ni] = __builtin_amdgcn_mfma_f32_16x16x32_f16(
            af[mi][1], bf[ni][1], acc[mi][ni], 0, 0, 0);
      }
    __builtin_amdgcn_s_setprio(0);
    asm volatile("s_waitcnt lgkmcnt(0)" ::: "memory");
    __builtin_amdgcn_s_barrier();  // all waves fully done reading dbuf[d]

    if (kt + 2 < NKT) PV_STAGE(kt + 2, d);
    __builtin_amdgcn_s_setprio(1);
#pragma unroll
    for (int mi = 0; mi < 4; ++mi)
#pragma unroll
      for (int ni = 2; ni < 4; ++ni) {
        acc[mi][ni] = __builtin_amdgcn_mfma_f32_16x16x32_f16(
            af[mi][0], bf[ni][0], acc[mi][ni], 0, 0, 0);
        acc[mi][ni] = __builtin_amdgcn_mfma_f32_16x16x32_f16(
            af[mi][1], bf[ni][1], acc[mi][ni], 0, 0, 0);
      }
    __builtin_amdgcn_s_setprio(0);
    if (kt + 2 < NKT) {
      asm volatile("s_waitcnt vmcnt(6)" ::: "memory");  // tile kt+1 landed
    } else if (kt + 1 < NKT) {
      asm volatile("s_waitcnt vmcnt(0)" ::: "memory");
    }
    __builtin_amdgcn_s_barrier();
  }
#undef PV_STAGE

  float* C = O + (size_t)bz * ((size_t)SEQ * DM);
#pragma unroll
  for (int mi = 0; mi < 4; ++mi)
#pragma unroll
    for (int ni = 0; ni < 4; ++ni)
#pragma unroll
      for (int r = 0; r < 4; ++r) {
        int grow = by * 128 + wr * 64 + mi * 16 + quad * 4 + r;
        int gcol = n0 + wc * 64 + ni * 16 + r16;
        C[(size_t)grow * DM + gcol] = acc[mi][ni][r];
      }
}

// ---------------- row softmax on packed fp16 scores, fp16 P in place ----------------
__global__ __launch_bounds__(256) void softmax_rows(_Float16* __restrict__ Sp) {
  __shared__ float vals[SEQ];
  __shared__ float red[256];
  int row = blockIdx.x;  // 0..NROWS-1
  int b = row >> 12;
  int q = row & (SEQ - 1);
  int i = q >> 7, r = q & 127;
  _Float16* base = Sp + (size_t)b * ((size_t)NT128 * TILE_ELE) +
                   (size_t)(i * (i + 1) / 2) * TILE_ELE + (size_t)r * 128;
  int tid = threadIdx.x;
  int Kv = q + 1;
  float m = -__builtin_inff();
  for (int kb = tid * 8; kb + 8 <= Kv; kb += 2048) {
    f16x8 v8 = *(const f16x8*)&base[(kb >> 7) * TILE_ELE + (kb & 127)];
#pragma unroll
    for (int t = 0; t < 8; ++t) {
      float v = (float)v8[t];
      vals[kb + t] = v;
      m = fmaxf(m, v);
    }
  }
  if (tid == 0) {
    for (int k = Kv & ~7; k < Kv; ++k) {
      float v = (float)base[(k >> 7) * TILE_ELE + (k & 127)];
      vals[k] = v;
      m = fmaxf(m, v);
    }
  }
  red[tid] = m;
  __syncthreads();
  for (int s = 128; s > 0; s >>= 1) {
    if (tid < s) red[tid] = fmaxf(red[tid], red[tid + s]);
    __syncthreads();
  }
  m = red[0];
  __syncthreads();
  float l = 0.f;
  for (int k = tid; k < Kv; k += 256) {
    float e = __expf(vals[k] - m);
    vals[k] = e;
    l += e;
  }
  red[tid] = l;
  __syncthreads();
  for (int s = 128; s > 0; s >>= 1) {
    if (tid < s) red[tid] += red[tid + s];
    __syncthreads();
  }
  float inv = 1.0f / red[0];
  int Kend = (i + 1) * 128;  // zero-fill to tile boundary (covers PV K-extent)
  for (int kb = tid * 8; kb < Kend; kb += 2048) {
    f16x8 p;
#pragma unroll
    for (int t = 0; t < 8; ++t) {
      int k = kb + t;
      p[t] = (k < Kv) ? (_Float16)(vals[k] * inv) : (_Float16)0.f;
    }
    *(f16x8*)&base[(kb >> 7) * TILE_ELE + (kb & 127)] = p;
  }
}

extern "C" void kernel_launch(void* const* d_in, const int* in_sizes, int n_in,
                              void* d_out, int out_size, void* d_ws,
                              size_t ws_size, hipStream_t stream) {
  const float* x = (const float*)d_in[0];
  const float* wq = (const float*)d_in[1];
  const float* wk = (const float*)d_in[2];
  const float* wv = (const float*)d_in[3];

  // Workspace layout (~98 MiB):
  //   [0, 69206016)            : Sp (packed tri fp16 scores)
  //     aliased early: xh [0,33554432) ; wqh/wkh/wvh [33554432, ...)
  //   [69206016, +33554432)    : vth (fp16 V^T, [B][DM][SEQ])
  char* ws = (char*)d_ws;
  _Float16* Sp = (_Float16*)ws;
  _Float16* xh = (_Float16*)ws;
  _Float16* wqh = (_Float16*)(ws + 33554432);
  _Float16* vth = (_Float16*)(ws + 69206016);
  _Float16* qh = (_Float16*)d_out;
  _Float16* kh = qh + (size_t)NROWS * DM;
  _Float16* wkh = wqh + (size_t)DM * DM;
  _Float16* wvh = wkh + (size_t)DM * DM;
  (void)ws_size; (void)in_sizes; (void)n_in; (void)out_size;

  static int attr_done = 0;
  if (!attr_done) {
    hipFuncSetAttribute(reinterpret_cast<const void*>(&gemm_p<4>),
                        hipFuncAttributeMaxDynamicSharedMemorySize, 131072);
    hipFuncSetAttribute(reinterpret_cast<const void*>(&gemm_p<1>),
                        hipFuncAttributeMaxDynamicSharedMemorySize, 131072);
    hipFuncSetAttribute(reinterpret_cast<const void*>(&gemm_pv),
                        hipFuncAttributeMaxDynamicSharedMemorySize, 98304);
    attr_done = 1;
  }

  // 1. fused fp32 -> fp16 converts (x + wq + wk + wv, one launch)
  cvt_all<<<9728, 256, 0, stream>>>(x, wq, wk, wv, xh, wqh);

  // 2. persistent merged QKV projections (256 blocks x 3 tiles)
  gemm_p<4><<<256, 512, 131072, stream>>>(xh, wqh, wkh, wvh, qh, kh, vth);

  // 3. RoPE q AND k in one launch (contiguous in d_out)
  rope_apply<<<2 * NROWS * HALF_D / 256, 256, 0, stream>>>(qh);

  // 4. persistent scores (256 blocks x 2-3 tri-tiles, no dead blocks)
  gemm_p<1><<<256, 512, 131072, stream>>>(qh, kh, nullptr, nullptr, Sp,
                                          nullptr, nullptr);

  // 5. softmax rows -> fp16 P in place
  softmax_rows<<<NROWS, 256, 0, stream>>>(Sp);

  // 6. O = P @ V (heavy-first 1D grid, 512 blocks)
  gemm_pv<<<512, 512, 98304, stream>>>(Sp, vth, (float*)d_out);
}

// Round 7
// 516.419 us; speedup vs baseline: 1.4064x; 1.4064x over previous
//
#include <hip/hip_runtime.h>

// Problem constants
#define BATCH 4
#define SEQ 4096
#define DM 1024
#define HALF_D 512             // DM/2 rope pairs
#define NROWS (BATCH * SEQ)    // 16384
#define NT128 528              // 32*33/2 lower-tri 128x128 tiles per batch
#define TILE_ELE 16384         // 128*128

typedef _Float16 f16x8 __attribute__((ext_vector_type(8)));
typedef _Float16 f16x4 __attribute__((ext_vector_type(4)));
typedef _Float16 f16x2 __attribute__((ext_vector_type(2)));
typedef float f32x4 __attribute__((ext_vector_type(4)));

#define AS1(p) ((const __attribute__((address_space(1))) void*)(p))
#define AS3(p) ((__attribute__((address_space(3))) void*)(p))

// ---------------- fused fp32 -> fp16 convert (x + wq + wk + wv) ----------------
__global__ __launch_bounds__(256) void cvt_all(
    const float* __restrict__ x, const float* __restrict__ wq,
    const float* __restrict__ wk, const float* __restrict__ wv,
    _Float16* __restrict__ xh, _Float16* __restrict__ wh /* wqh base */) {
  int i = blockIdx.x * 256 + threadIdx.x;
  const int NX = NROWS * DM / 8;  // 2097152
  const int NW = DM * DM / 8;     // 131072
  const float* src;
  _Float16* dst;
  int so;
  if (i < NX) {
    src = x; so = i; dst = xh + 8 * (size_t)i;
  } else {
    int j = i - NX;
    if (j >= 3 * NW) return;
    dst = wh + 8 * (size_t)j;  // wqh/wkh/wvh contiguous in ws
    if (j < NW) { src = wq; so = j; }
    else if (j < 2 * NW) { src = wk; so = j - NW; }
    else { src = wv; so = j - 2 * NW; }
  }
  const float4* s4 = (const float4*)src;
  float4 a = s4[2 * so], b = s4[2 * so + 1];
  f16x8 h;
  h[0] = (_Float16)a.x; h[1] = (_Float16)a.y;
  h[2] = (_Float16)a.z; h[3] = (_Float16)a.w;
  h[4] = (_Float16)b.x; h[5] = (_Float16)b.y;
  h[6] = (_Float16)b.z; h[7] = (_Float16)b.w;
  *(f16x8*)dst = h;
}

// ---------------- RoPE apply in place; single launch covers q AND k ----------------
__global__ __launch_bounds__(256) void rope_apply(_Float16* __restrict__ T) {
  int idx = blockIdx.x * 256 + threadIdx.x;  // 2*NROWS*HALF_D
  int row = idx >> 9;
  int i = idx & 511;
  int pos = row & (SEQ - 1);
  float theta = expf(-0.017988946039016f * ((float)i - 1.0f));  // 10000^(-2(i-1)/DM)
  float ang = (float)pos * theta;
  float c = cosf(ang), s = sinf(ang);
  f16x2 p = ((f16x2*)T)[idx];
  float e = (float)p[0], o = (float)p[1];
  p[0] = (_Float16)(e * c + o * s);
  p[1] = (_Float16)(o * c - e * s);
  ((f16x2*)T)[idx] = p;
}

// =====================================================================
// PERSISTENT QKV: 256 blocks, each computes Q, K, V tiles for its fixed
// (m,n) panel. Per-slot phase/barrier/vmcnt structure is byte-identical to
// the verified round-4 schedule. Spill-proofing vs round-5 failure:
//  - nkt is a RUNTIME arg (round-4 parity: kt loop not unrollable)
//  - unroll(disable) on j and kt loops
//  - A panel FIXED across tiles (no next-A descriptor), B rolls wq->wk->wv
// Steady state at phase-4 wait: queue = [A(s+1) done, B(s+1) done, A(s+2)
// in flight] -> vmcnt(4). Cross-tile: A wraps modulo nkt on the same base;
// B(kt==15) stages Bnext. LDS parity continuous (nkt even).
// =====================================================================
__global__ __launch_bounds__(512, 2) void gemm_qkv_p(
    const _Float16* __restrict__ X, const _Float16* __restrict__ Wq,
    const _Float16* __restrict__ Wk, const _Float16* __restrict__ Wv,
    _Float16* __restrict__ Qo, _Float16* __restrict__ Ko,
    _Float16* __restrict__ Vt, int nkt) {
  extern __shared__ __align__(16) _Float16 lds[];  // 128 KiB
  const int bid = blockIdx.x;
  const int tid = threadIdx.x;
  const int lane = tid & 63, wave = tid >> 6;
  const int wr = wave >> 2, wc = wave & 3;  // 2x4 wave grid
  const int r16 = lane & 15, quad = lane >> 4;
  const int qm0 = (bid >> 2) * 256, qn0 = (bid & 3) * 256;

  // per-thread staging offsets, source col pre-swizzled
  int offs[2][2];
#pragma unroll
  for (int i = 0; i < 2; ++i) {
    int c = i * 512 + tid;
    int row = c >> 3;
    int scol = (c & 7) ^ (row & 7);
#pragma unroll
    for (int h = 0; h < 2; ++h) offs[h][i] = (h * 128 + row) * DM + scol * 8;
  }

  const _Float16* Ag = X + (size_t)qm0 * DM;        // fixed across all tiles
  const _Float16* Bcur = Wq + (size_t)qn0 * DM;
  const _Float16* Bnext = Wk + (size_t)qn0 * DM;

#define STAGE_A(BASE, ktv, dd)                                              \
  {                                                                         \
    _Pragma("unroll") for (int i = 0; i < 2; ++i) {                         \
      int cu = (i * 512 + wave * 64) * 8;                                   \
      _Pragma("unroll") for (int h = 0; h < 2; ++h)                         \
          __builtin_amdgcn_global_load_lds(                                 \
              AS1(BASE + offs[h][i] + (ktv) * 64),                          \
              AS3(&lds[((dd) * 4 + h) * 8192 + cu]), 16, 0, 0);             \
    }                                                                       \
  }
#define STAGE_B(BASE, ktv, dd)                                              \
  {                                                                         \
    _Pragma("unroll") for (int i = 0; i < 2; ++i) {                         \
      int cu = (i * 512 + wave * 64) * 8;                                   \
      _Pragma("unroll") for (int h = 0; h < 2; ++h)                         \
          __builtin_amdgcn_global_load_lds(                                 \
              AS1(BASE + offs[h][i] + (ktv) * 64),                          \
              AS3(&lds[((dd) * 4 + 2 + h) * 8192 + cu]), 16, 0, 0);         \
    }                                                                       \
  }

  f32x4 acc[8][4] = {};
  const int aoff0 = ((quad) ^ (r16 & 7)) * 8;
  const int aoff1 = ((4 + quad) ^ (r16 & 7)) * 8;
  const int NS = 3 * nkt;

  // prologue: A0,B0 of tile 0 + A1 in flight; wait A0,B0
  STAGE_A(Ag, 0, 0);
  STAGE_B(Bcur, 0, 0);
  STAGE_A(Ag, 1, 1);
  asm volatile("s_waitcnt vmcnt(4)" ::: "memory");
  __builtin_amdgcn_s_barrier();

  int s = 0;
#pragma clang loop unroll(disable)
  for (int j = 0; j < 3; ++j) {
#pragma clang loop unroll(disable)
    for (int kt = 0; kt < nkt; ++kt, ++s) {
      const int d = s & 1;
      const _Float16* Ab = lds + (d * 4 + wr) * 8192;
      const _Float16* Bb =
          lds + (d * 4 + 2 + (wc >> 1)) * 8192 + (wc & 1) * 4096;
      f16x8 af[4][2], bf[4][2];

      // phase 1: issue B(s+1); read af(0-3)+bf(0-1); MFMA G0
      if (s + 1 < NS) {
        if (kt + 1 < nkt) { STAGE_B(Bcur, kt + 1, d ^ 1); }
        else              { STAGE_B(Bnext, 0, d ^ 1); }
      }
#pragma unroll
      for (int mi = 0; mi < 4; ++mi) {
        af[mi][0] = *(const f16x8*)&Ab[(mi * 16 + r16) * 64 + aoff0];
        af[mi][1] = *(const f16x8*)&Ab[(mi * 16 + r16) * 64 + aoff1];
      }
#pragma unroll
      for (int ni = 0; ni < 2; ++ni) {
        bf[ni][0] = *(const f16x8*)&Bb[(ni * 16 + r16) * 64 + aoff0];
        bf[ni][1] = *(const f16x8*)&Bb[(ni * 16 + r16) * 64 + aoff1];
      }
      __builtin_amdgcn_s_barrier();
      __builtin_amdgcn_s_setprio(1);
#pragma unroll
      for (int mi = 0; mi < 4; ++mi)
#pragma unroll
        for (int ni = 0; ni < 2; ++ni) {
          acc[mi][ni] = __builtin_amdgcn_mfma_f32_16x16x32_f16(
              af[mi][0], bf[ni][0], acc[mi][ni], 0, 0, 0);
          acc[mi][ni] = __builtin_amdgcn_mfma_f32_16x16x32_f16(
              af[mi][1], bf[ni][1], acc[mi][ni], 0, 0, 0);
        }
      __builtin_amdgcn_s_setprio(0);
      __builtin_amdgcn_s_barrier();

      // phase 2: read bf(2-3); MFMA G1
#pragma unroll
      for (int ni = 2; ni < 4; ++ni) {
        bf[ni][0] = *(const f16x8*)&Bb[(ni * 16 + r16) * 64 + aoff0];
        bf[ni][1] = *(const f16x8*)&Bb[(ni * 16 + r16) * 64 + aoff1];
      }
      __builtin_amdgcn_s_barrier();
      __builtin_amdgcn_s_setprio(1);
#pragma unroll
      for (int mi = 0; mi < 4; ++mi)
#pragma unroll
        for (int ni = 2; ni < 4; ++ni) {
          acc[mi][ni] = __builtin_amdgcn_mfma_f32_16x16x32_f16(
              af[mi][0], bf[ni][0], acc[mi][ni], 0, 0, 0);
          acc[mi][ni] = __builtin_amdgcn_mfma_f32_16x16x32_f16(
              af[mi][1], bf[ni][1], acc[mi][ni], 0, 0, 0);
        }
      __builtin_amdgcn_s_setprio(0);
      __builtin_amdgcn_s_barrier();

      // phase 3: read af(4-7); MFMA G2
#pragma unroll
      for (int mi = 0; mi < 4; ++mi) {
        af[mi][0] = *(const f16x8*)&Ab[((mi + 4) * 16 + r16) * 64 + aoff0];
        af[mi][1] = *(const f16x8*)&Ab[((mi + 4) * 16 + r16) * 64 + aoff1];
      }
      __builtin_amdgcn_s_barrier();
      __builtin_amdgcn_s_setprio(1);
#pragma unroll
      for (int mi = 0; mi < 4; ++mi)
#pragma unroll
        for (int ni = 0; ni < 2; ++ni) {
          acc[mi + 4][ni] = __builtin_amdgcn_mfma_f32_16x16x32_f16(
              af[mi][0], bf[ni][0], acc[mi + 4][ni], 0, 0, 0);
          acc[mi + 4][ni] = __builtin_amdgcn_mfma_f32_16x16x32_f16(
              af[mi][1], bf[ni][1], acc[mi + 4][ni], 0, 0, 0);
        }
      __builtin_amdgcn_s_setprio(0);
      __builtin_amdgcn_s_barrier();
      // all waves' reads of dbuf[d] are complete

      // phase 4: issue A(s+2) -> dbuf[d]; MFMA G3; counted wait
      if (s + 2 < NS) {
        int ktv = (kt + 2 < nkt) ? kt + 2 : kt + 2 - nkt;  // A base fixed
        STAGE_A(Ag, ktv, d);
      }
      __builtin_amdgcn_s_setprio(1);
#pragma unroll
      for (int mi = 0; mi < 4; ++mi)
#pragma unroll
        for (int ni = 2; ni < 4; ++ni) {
          acc[mi + 4][ni] = __builtin_amdgcn_mfma_f32_16x16x32_f16(
              af[mi][0], bf[ni][0], acc[mi + 4][ni], 0, 0, 0);
          acc[mi + 4][ni] = __builtin_amdgcn_mfma_f32_16x16x32_f16(
              af[mi][1], bf[ni][1], acc[mi + 4][ni], 0, 0, 0);
        }
      __builtin_amdgcn_s_setprio(0);
      if (s + 2 < NS) {
        asm volatile("s_waitcnt vmcnt(4)" ::: "memory");  // slot s+1 landed
      } else if (s + 1 < NS) {
        asm volatile("s_waitcnt vmcnt(0)" ::: "memory");
      }
      __builtin_amdgcn_s_barrier();
    }

    // ---- epilogue for tile j (next tile's loads already in flight) ----
    if (j < 2) {  // Q or K: row-major fp16
      _Float16* C = (j == 0) ? Qo : Ko;
#pragma unroll
      for (int mi = 0; mi < 8; ++mi)
#pragma unroll
        for (int ni = 0; ni < 4; ++ni)
#pragma unroll
          for (int r = 0; r < 4; ++r) {
            int grow = qm0 + wr * 128 + mi * 16 + quad * 4 + r;
            int gcol = qn0 + wc * 64 + ni * 16 + r16;
            C[(size_t)grow * DM + gcol] = (_Float16)acc[mi][ni][r];
          }
    } else {  // V -> Vt[b][d][m]
#pragma unroll
      for (int mi = 0; mi < 8; ++mi)
#pragma unroll
        for (int ni = 0; ni < 4; ++ni) {
          int gcol = qn0 + wc * 64 + ni * 16 + r16;         // d
          int growb = qm0 + wr * 128 + mi * 16 + quad * 4;  // m base
          int b = growb >> 12;
          int m = growb & (SEQ - 1);
          f16x4 t;
#pragma unroll
          for (int r = 0; r < 4; ++r) t[r] = (_Float16)acc[mi][ni][r];
          *(f16x4*)&Vt[((size_t)b * DM + gcol) * SEQ + m] = t;
        }
    }

    // reset accumulators; roll B pointer
#pragma unroll
    for (int mi = 0; mi < 8; ++mi)
#pragma unroll
      for (int ni = 0; ni < 4; ++ni)
#pragma unroll
        for (int r = 0; r < 4; ++r) acc[mi][ni][r] = 0.f;
    Bcur = Bnext;
    Bnext = Wv + (size_t)qn0 * DM;
  }
#undef STAGE_A
#undef STAGE_B
}

// =====================================================================
// Scores: S = Q@K^T * 1/32, causal; EXACT round-4 verified kernel
// (spread staging, XOR swizzle, counted vmcnt(4), runtime K bound).
// Epilogue: 128x128 quadrants -> packed lower-tri 128-tile layout.
// =====================================================================
__global__ __launch_bounds__(512, 2) void gemm_s(
    const _Float16* __restrict__ Q, const _Float16* __restrict__ Kh,
    _Float16* __restrict__ Sp, int K) {
  const int bx = blockIdx.x, by = blockIdx.y, bz = blockIdx.z;
  if (bx > by) return;  // fully above diagonal (256-granular)
  const _Float16* Asel = Q + (size_t)bz * ((size_t)SEQ * DM);
  const _Float16* Bsel = Kh + (size_t)bz * ((size_t)SEQ * DM);

  extern __shared__ __align__(16) _Float16 lds[];  // 128 KiB

  const int tid = threadIdx.x;
  const int lane = tid & 63, wave = tid >> 6;
  const int wr = wave >> 2, wc = wave & 3;
  const int r16 = lane & 15, quad = lane >> 4;
  const int m0 = by * 256, n0 = bx * 256;

  const _Float16* pA[2][2];
  const _Float16* pB[2][2];
#pragma unroll
  for (int i = 0; i < 2; ++i) {
    int c = i * 512 + tid;
    int row = c >> 3;
    int scol = (c & 7) ^ (row & 7);
#pragma unroll
    for (int h = 0; h < 2; ++h) {
      pA[h][i] = Asel + (size_t)(m0 + h * 128 + row) * DM + scol * 8;
      pB[h][i] = Bsel + (size_t)(n0 + h * 128 + row) * DM + scol * 8;
    }
  }

#define STAGE_A(d)                                                           \
  {                                                                          \
    _Pragma("unroll") for (int i = 0; i < 2; ++i) {                          \
      int cu = (i * 512 + wave * 64) * 8;                                    \
      _Pragma("unroll") for (int h = 0; h < 2; ++h) {                        \
        __builtin_amdgcn_global_load_lds(                                    \
            AS1(pA[h][i]), AS3(&lds[((d) * 4 + h) * 8192 + cu]), 16, 0, 0);  \
        pA[h][i] += 64;                                                      \
      }                                                                      \
    }                                                                        \
  }
#define STAGE_B(d)                                                           \
  {                                                                          \
    _Pragma("unroll") for (int i = 0; i < 2; ++i) {                          \
      int cu = (i * 512 + wave * 64) * 8;                                    \
      _Pragma("unroll") for (int h = 0; h < 2; ++h) {                        \
        __builtin_amdgcn_global_load_lds(                                    \
            AS1(pB[h][i]), AS3(&lds[((d) * 4 + 2 + h) * 8192 + cu]), 16, 0,  \
            0);                                                              \
        pB[h][i] += 64;                                                      \
      }                                                                      \
    }                                                                        \
  }

  f32x4 acc[8][4] = {};

  const int NKT = K >> 6;

  const int aoff0 = ((quad) ^ (r16 & 7)) * 8;
  const int aoff1 = ((4 + quad) ^ (r16 & 7)) * 8;

  STAGE_A(0);
  STAGE_B(0);
  STAGE_A(1);
  asm volatile("s_waitcnt vmcnt(4)" ::: "memory");
  __builtin_amdgcn_s_barrier();

  for (int kt = 0; kt < NKT; ++kt) {
    const int d = kt & 1;
    const _Float16* Ab = lds + (d * 4 + wr) * 8192;
    const _Float16* Bb = lds + (d * 4 + 2 + (wc >> 1)) * 8192 + (wc & 1) * 4096;
    f16x8 af[4][2], bf[4][2];

    // phase 1: issue B(kt+1) -> dbuf[d^1]; read af(0-3)+bf(0-1); MFMA G0
    if (kt + 1 < NKT) STAGE_B(d ^ 1);
#pragma unroll
    for (int mi = 0; mi < 4; ++mi) {
      af[mi][0] = *(const f16x8*)&Ab[(mi * 16 + r16) * 64 + aoff0];
      af[mi][1] = *(const f16x8*)&Ab[(mi * 16 + r16) * 64 + aoff1];
    }
#pragma unroll
    for (int ni = 0; ni < 2; ++ni) {
      bf[ni][0] = *(const f16x8*)&Bb[(ni * 16 + r16) * 64 + aoff0];
      bf[ni][1] = *(const f16x8*)&Bb[(ni * 16 + r16) * 64 + aoff1];
    }
    __builtin_amdgcn_s_barrier();
    __builtin_amdgcn_s_setprio(1);
#pragma unroll
    for (int mi = 0; mi < 4; ++mi)
#pragma unroll
      for (int ni = 0; ni < 2; ++ni) {
        acc[mi][ni] = __builtin_amdgcn_mfma_f32_16x16x32_f16(
            af[mi][0], bf[ni][0], acc[mi][ni], 0, 0, 0);
        acc[mi][ni] = __builtin_amdgcn_mfma_f32_16x16x32_f16(
            af[mi][1], bf[ni][1], acc[mi][ni], 0, 0, 0);
      }
    __builtin_amdgcn_s_setprio(0);
    __builtin_amdgcn_s_barrier();

    // phase 2: read bf(2-3); MFMA G1
#pragma unroll
    for (int ni = 2; ni < 4; ++ni) {
      bf[ni][0] = *(const f16x8*)&Bb[(ni * 16 + r16) * 64 + aoff0];
      bf[ni][1] = *(const f16x8*)&Bb[(ni * 16 + r16) * 64 + aoff1];
    }
    __builtin_amdgcn_s_barrier();
    __builtin_amdgcn_s_setprio(1);
#pragma unroll
    for (int mi = 0; mi < 4; ++mi)
#pragma unroll
      for (int ni = 2; ni < 4; ++ni) {
        acc[mi][ni] = __builtin_amdgcn_mfma_f32_16x16x32_f16(
            af[mi][0], bf[ni][0], acc[mi][ni], 0, 0, 0);
        acc[mi][ni] = __builtin_amdgcn_mfma_f32_16x16x32_f16(
            af[mi][1], bf[ni][1], acc[mi][ni], 0, 0, 0);
      }
    __builtin_amdgcn_s_setprio(0);
    __builtin_amdgcn_s_barrier();

    // phase 3: read af(4-7); MFMA G2
#pragma unroll
    for (int mi = 0; mi < 4; ++mi) {
      af[mi][0] = *(const f16x8*)&Ab[((mi + 4) * 16 + r16) * 64 + aoff0];
      af[mi][1] = *(const f16x8*)&Ab[((mi + 4) * 16 + r16) * 64 + aoff1];
    }
    __builtin_amdgcn_s_barrier();
    __builtin_amdgcn_s_setprio(1);
#pragma unroll
    for (int mi = 0; mi < 4; ++mi)
#pragma unroll
      for (int ni = 0; ni < 2; ++ni) {
        acc[mi + 4][ni] = __builtin_amdgcn_mfma_f32_16x16x32_f16(
            af[mi][0], bf[ni][0], acc[mi + 4][ni], 0, 0, 0);
        acc[mi + 4][ni] = __builtin_amdgcn_mfma_f32_16x16x32_f16(
            af[mi][1], bf[ni][1], acc[mi + 4][ni], 0, 0, 0);
      }
    __builtin_amdgcn_s_setprio(0);
    __builtin_amdgcn_s_barrier();

    // phase 4: issue A(kt+2) -> dbuf[d]; MFMA G3; counted wait
    if (kt + 2 < NKT) STAGE_A(d);
    __builtin_amdgcn_s_setprio(1);
#pragma unroll
    for (int mi = 0; mi < 4; ++mi)
#pragma unroll
      for (int ni = 2; ni < 4; ++ni) {
        acc[mi + 4][ni] = __builtin_amdgcn_mfma_f32_16x16x32_f16(
            af[mi][0], bf[ni][0], acc[mi + 4][ni], 0, 0, 0);
        acc[mi + 4][ni] = __builtin_amdgcn_mfma_f32_16x16x32_f16(
            af[mi][1], bf[ni][1], acc[mi + 4][ni], 0, 0, 0);
      }
    __builtin_amdgcn_s_setprio(0);
    if (kt + 2 < NKT) {
      asm volatile("s_waitcnt vmcnt(4)" ::: "memory");
    } else if (kt + 1 < NKT) {
      asm volatile("s_waitcnt vmcnt(0)" ::: "memory");
    }
    __builtin_amdgcn_s_barrier();
  }
#undef STAGE_A
#undef STAGE_B

  // epilogue: 128x128 quadrants into packed lower-tri layout
  int i128 = by * 2 + wr;
  int j128 = bx * 2 + (wc >> 1);
  if (j128 <= i128) {
    _Float16* T = Sp + (size_t)bz * ((size_t)NT128 * TILE_ELE) +
                  (size_t)(i128 * (i128 + 1) / 2 + j128) * TILE_ELE;
#pragma unroll
    for (int mi = 0; mi < 8; ++mi)
#pragma unroll
      for (int ni = 0; ni < 4; ++ni)
#pragma unroll
        for (int r = 0; r < 4; ++r) {
          int lr = mi * 16 + quad * 4 + r;         // 0..127
          int lc = (wc & 1) * 64 + ni * 16 + r16;  // 0..127
          T[lr * 128 + lc] = (_Float16)(acc[mi][ni][r] * 0.03125f);
        }
  }
}

// =====================================================================
// PV: O = P @ V, 128x256-tile NT GEMM, BK=64 (round-4 verified, unchanged)
// =====================================================================
__global__ __launch_bounds__(512, 1) void gemm_pv(
    const _Float16* __restrict__ P, const _Float16* __restrict__ Vt,
    float* __restrict__ O) {
  const int id = blockIdx.x;
  const int by = 31 - (id >> 4);  // heavy (large K) first
  const int bx = id & 3;          // DM/256 col-tile
  const int bz = (id >> 2) & 3;   // batch

  extern __shared__ __align__(16) _Float16 lds[];  // 49152 f16 = 96 KiB

  const int tid = threadIdx.x;
  const int lane = tid & 63, wave = tid >> 6;
  const int wr = wave >> 2, wc = wave & 3;
  const int r16 = lane & 15, quad = lane >> 4;
  const int n0 = bx * 256;

  const _Float16* Pb = P + (size_t)bz * ((size_t)NT128 * TILE_ELE) +
                       (size_t)(by * (by + 1) / 2) * TILE_ELE;
  const _Float16* Vb = Vt + (size_t)bz * ((size_t)DM * SEQ) + (size_t)n0 * SEQ;

  const int NKT = (by + 1) * 2;  // even, >= 2

#define PV_STAGE(t, dd)                                                      \
  {                                                                          \
    _Pragma("unroll") for (int i = 0; i < 2; ++i) {                          \
      int c = i * 512 + tid;                                                 \
      int row = c >> 3;                                                      \
      int scol = (c & 7) ^ (row & 7);                                        \
      const _Float16* gA = Pb + (size_t)((t) >> 1) * TILE_ELE + row * 128 +  \
                           ((t) & 1) * 64 + scol * 8;                        \
      __builtin_amdgcn_global_load_lds(                                      \
          AS1(gA), AS3(&lds[(dd) * 24576 + (i * 512 + wave * 64) * 8]), 16,  \
          0, 0);                                                             \
    }                                                                        \
    _Pragma("unroll") for (int i = 0; i < 4; ++i) {                          \
      int c = i * 512 + tid;                                                 \
      int row = c >> 3;                                                      \
      int scol = (c & 7) ^ (row & 7);                                        \
      const _Float16* gB = Vb + (size_t)row * SEQ + (t) * 64 + scol * 8;     \
      __builtin_amdgcn_global_load_lds(                                      \
          AS1(gB),                                                           \
          AS3(&lds[(dd) * 24576 + 8192 + (i * 512 + wave * 64) * 8]), 16, 0, \
          0);                                                                \
    }                                                                        \
  }

  f32x4 acc[4][4] = {};

  const int aoff0 = ((quad) ^ (r16 & 7)) * 8;
  const int aoff1 = ((4 + quad) ^ (r16 & 7)) * 8;
  const int arow = (wr * 64 + r16) * 64;
  const int brow = (wc * 64 + r16) * 64;

  PV_STAGE(0, 0);
  PV_STAGE(1, 1);
  asm volatile("s_waitcnt vmcnt(6)" ::: "memory");
  __builtin_amdgcn_s_barrier();

  for (int kt = 0; kt < NKT; ++kt) {
    const int d = kt & 1;
    const _Float16* Ab = lds + d * 24576;
    const _Float16* Bb = Ab + 8192;
    f16x8 af[4][2], bf[4][2];

#pragma unroll
    for (int mi = 0; mi < 4; ++mi) {
      af[mi][0] = *(const f16x8*)&Ab[arow + mi * 16 * 64 + aoff0];
      af[mi][1] = *(const f16x8*)&Ab[arow + mi * 16 * 64 + aoff1];
    }
#pragma unroll
    for (int ni = 0; ni < 4; ++ni) {
      bf[ni][0] = *(const f16x8*)&Bb[brow + ni * 16 * 64 + aoff0];
      bf[ni][1] = *(const f16x8*)&Bb[brow + ni * 16 * 64 + aoff1];
    }
    __builtin_amdgcn_s_barrier();
    __builtin_amdgcn_s_setprio(1);
#pragma unroll
    for (int mi = 0; mi < 4; ++mi)
#pragma unroll
      for (int ni = 0; ni < 2; ++ni) {
        acc[mi][ni] = __builtin_amdgcn_mfma_f32_16x16x32_f16(
            af[mi][0], bf[ni][0], acc[mi][ni], 0, 0, 0);
        acc[mi][ni] = __builtin_amdgcn_mfma_f32_16x16x32_f16(
            af[mi][1], bf[ni][1], acc[mi][ni], 0, 0, 0);
      }
    __builtin_amdgcn_s_setprio(0);
    asm volatile("s_waitcnt lgkmcnt(0)" ::: "memory");
    __builtin_amdgcn_s_barrier();  // all waves fully done reading dbuf[d]

    if (kt + 2 < NKT) PV_STAGE(kt + 2, d);
    __builtin_amdgcn_s_setprio(1);
#pragma unroll
    for (int mi = 0; mi < 4; ++mi)
#pragma unroll
      for (int ni = 2; ni < 4; ++ni) {
        acc[mi][ni] = __builtin_amdgcn_mfma_f32_16x16x32_f16(
            af[mi][0], bf[ni][0], acc[mi][ni], 0, 0, 0);
        acc[mi][ni] = __builtin_amdgcn_mfma_f32_16x16x32_f16(
            af[mi][1], bf[ni][1], acc[mi][ni], 0, 0, 0);
      }
    __builtin_amdgcn_s_setprio(0);
    if (kt + 2 < NKT) {
      asm volatile("s_waitcnt vmcnt(6)" ::: "memory");
    } else if (kt + 1 < NKT) {
      asm volatile("s_waitcnt vmcnt(0)" ::: "memory");
    }
    __builtin_amdgcn_s_barrier();
  }
#undef PV_STAGE

  float* C = O + (size_t)bz * ((size_t)SEQ * DM);
#pragma unroll
  for (int mi = 0; mi < 4; ++mi)
#pragma unroll
    for (int ni = 0; ni < 4; ++ni)
#pragma unroll
      for (int r = 0; r < 4; ++r) {
        int grow = by * 128 + wr * 64 + mi * 16 + quad * 4 + r;
        int gcol = n0 + wc * 64 + ni * 16 + r16;
        C[(size_t)grow * DM + gcol] = acc[mi][ni][r];
      }
}

// ---------------- row softmax on packed fp16 scores, fp16 P in place ----------------
__global__ __launch_bounds__(256) void softmax_rows(_Float16* __restrict__ Sp) {
  __shared__ float vals[SEQ];
  __shared__ float red[256];
  int row = blockIdx.x;  // 0..NROWS-1
  int b = row >> 12;
  int q = row & (SEQ - 1);
  int i = q >> 7, r = q & 127;
  _Float16* base = Sp + (size_t)b * ((size_t)NT128 * TILE_ELE) +
                   (size_t)(i * (i + 1) / 2) * TILE_ELE + (size_t)r * 128;
  int tid = threadIdx.x;
  int Kv = q + 1;
  float m = -__builtin_inff();
  for (int kb = tid * 8; kb + 8 <= Kv; kb += 2048) {
    f16x8 v8 = *(const f16x8*)&base[(kb >> 7) * TILE_ELE + (kb & 127)];
#pragma unroll
    for (int t = 0; t < 8; ++t) {
      float v = (float)v8[t];
      vals[kb + t] = v;
      m = fmaxf(m, v);
    }
  }
  if (tid == 0) {
    for (int k = Kv & ~7; k < Kv; ++k) {
      float v = (float)base[(k >> 7) * TILE_ELE + (k & 127)];
      vals[k] = v;
      m = fmaxf(m, v);
    }
  }
  red[tid] = m;
  __syncthreads();
  for (int s = 128; s > 0; s >>= 1) {
    if (tid < s) red[tid] = fmaxf(red[tid], red[tid + s]);
    __syncthreads();
  }
  m = red[0];
  __syncthreads();
  float l = 0.f;
  for (int k = tid; k < Kv; k += 256) {
    float e = __expf(vals[k] - m);
    vals[k] = e;
    l += e;
  }
  red[tid] = l;
  __syncthreads();
  for (int s = 128; s > 0; s >>= 1) {
    if (tid < s) red[tid] += red[tid + s];
    __syncthreads();
  }
  float inv = 1.0f / red[0];
  int Kend = (i + 1) * 128;  // zero-fill to tile boundary (covers PV K-extent)
  for (int kb = tid * 8; kb < Kend; kb += 2048) {
    f16x8 p;
#pragma unroll
    for (int t = 0; t < 8; ++t) {
      int k = kb + t;
      p[t] = (k < Kv) ? (_Float16)(vals[k] * inv) : (_Float16)0.f;
    }
    *(f16x8*)&base[(kb >> 7) * TILE_ELE + (kb & 127)] = p;
  }
}

extern "C" void kernel_launch(void* const* d_in, const int* in_sizes, int n_in,
                              void* d_out, int out_size, void* d_ws,
                              size_t ws_size, hipStream_t stream) {
  const float* x = (const float*)d_in[0];
  const float* wq = (const float*)d_in[1];
  const float* wk = (const float*)d_in[2];
  const float* wv = (const float*)d_in[3];

  // Workspace layout (~98 MiB):
  //   [0, 69206016)            : Sp (packed tri fp16 scores)
  //     aliased early: xh [0,33554432) ; wqh/wkh/wvh [33554432, ...)
  //   [69206016, +33554432)    : vth (fp16 V^T, [B][DM][SEQ])
  char* ws = (char*)d_ws;
  _Float16* Sp = (_Float16*)ws;
  _Float16* xh = (_Float16*)ws;
  _Float16* wqh = (_Float16*)(ws + 33554432);
  _Float16* vth = (_Float16*)(ws + 69206016);
  _Float16* qh = (_Float16*)d_out;
  _Float16* kh = qh + (size_t)NROWS * DM;
  _Float16* wkh = wqh + (size_t)DM * DM;
  _Float16* wvh = wkh + (size_t)DM * DM;
  (void)ws_size; (void)in_sizes; (void)n_in; (void)out_size;

  static int attr_done = 0;
  if (!attr_done) {
    hipFuncSetAttribute(reinterpret_cast<const void*>(&gemm_qkv_p),
                        hipFuncAttributeMaxDynamicSharedMemorySize, 131072);
    hipFuncSetAttribute(reinterpret_cast<const void*>(&gemm_s),
                        hipFuncAttributeMaxDynamicSharedMemorySize, 131072);
    hipFuncSetAttribute(reinterpret_cast<const void*>(&gemm_pv),
                        hipFuncAttributeMaxDynamicSharedMemorySize, 98304);
    attr_done = 1;
  }

  // 1. fused fp32 -> fp16 converts (one launch)
  cvt_all<<<9728, 256, 0, stream>>>(x, wq, wk, wv, xh, wqh);

  // 2. persistent QKV projections (256 blocks x {Q,K,V}; nkt runtime = 16)
  gemm_qkv_p<<<256, 512, 131072, stream>>>(xh, wqh, wkh, wvh, qh, kh, vth,
                                           DM / 64);

  // 3. RoPE q AND k in one launch (contiguous in d_out)
  rope_apply<<<2 * NROWS * HALF_D / 256, 256, 0, stream>>>(qh);

  // 4. scores (round-4 verified kernel, runtime K)
  gemm_s<<<dim3(SEQ / 256, SEQ / 256, BATCH), 512, 131072, stream>>>(qh, kh,
                                                                     Sp, DM);

  // 5. softmax rows -> fp16 P in place
  softmax_rows<<<NROWS, 256, 0, stream>>>(Sp);

  // 6. O = P @ V (heavy-first 1D grid, 512 blocks)
  gemm_pv<<<512, 512, 98304, stream>>>(Sp, vth, (float*)d_out);
}